// Round 1
// baseline (502.388 us; speedup 1.0000x reference)
//
#include <hip/hip_runtime.h>

// MSPushPullLoss: B=16, C=16, labels 0..16, seg = b*17+lab, NSEG=272.
// Scales: (16,1024,1024) (16,512,512) (16,256,256).
// Two streaming passes (sum/cnt, then pull values), tiny mean + finalize kernels.

#define NSEG 272
#define NW 4           // waves per 256-thread block
#define M_VAR 0.1f
#define TWO_M_DIST 3.0f

__device__ __forceinline__ void gatomic_add(float* p, float v) {
  __hip_atomic_fetch_add(p, v, __ATOMIC_RELAXED, __HIP_MEMORY_SCOPE_AGENT);
}

// Block partition: blocks [0,1024) -> scale0, [1024,1280) -> scale1, [1280,1344) -> scale2.
// Per-scale vec counts (float4): 2^22 / 2^20 / 2^18; per-batch vecs: 2^18 / 2^16 / 2^14.
#define GRID_BLOCKS 1344

struct ScaleSel {
  const float4* f; const int4* g;
  int vstart, nblocks, nvec, logSv, scale;
};

__device__ __forceinline__ ScaleSel select_scale(
    int b,
    const float4* f0, const int4* g0,
    const float4* f1, const int4* g1,
    const float4* f2, const int4* g2) {
  ScaleSel s;
  if (b < 1024)      { s.f=f0; s.g=g0; s.vstart=b;      s.nblocks=1024; s.nvec=1<<22; s.logSv=18; s.scale=0; }
  else if (b < 1280) { s.f=f1; s.g=g1; s.vstart=b-1024; s.nblocks=256;  s.nvec=1<<20; s.logSv=16; s.scale=1; }
  else               { s.f=f2; s.g=g2; s.vstart=b-1280; s.nblocks=64;   s.nvec=1<<18; s.logSv=14; s.scale=2; }
  return s;
}

__global__ __launch_bounds__(256, 4) void pass1_kernel(
    const float4* __restrict__ f0, const int4* __restrict__ g0,
    const float4* __restrict__ f1, const int4* __restrict__ g1,
    const float4* __restrict__ f2, const int4* __restrict__ g2,
    float* __restrict__ tot_sum,   // [NSEG]
    float* __restrict__ cnt)       // [3][NSEG]
{
  __shared__ float s_sum[NW][NSEG];
  __shared__ float s_cnt[NW][NSEG];
  const int tid = threadIdx.x;
  const int wave = tid >> 6;
  for (int i = tid; i < NW * NSEG; i += 256) {
    (&s_sum[0][0])[i] = 0.f;
    (&s_cnt[0][0])[i] = 0.f;
  }
  __syncthreads();

  ScaleSel s = select_scale(blockIdx.x, f0, g0, f1, g1, f2, g2);
  float* ms = s_sum[wave];
  float* mc = s_cnt[wave];

  for (int v = s.vstart * 256 + tid; v < s.nvec; v += s.nblocks * 256) {
    float4 fv = s.f[v];
    int4   gv = s.g[v];
    int base = (v >> s.logSv) * 17;
    int l;
    l = gv.x; if ((unsigned)(l - 1) < 16u) { atomicAdd(&ms[base + l], fv.x); atomicAdd(&mc[base + l], 1.f); }
    l = gv.y; if ((unsigned)(l - 1) < 16u) { atomicAdd(&ms[base + l], fv.y); atomicAdd(&mc[base + l], 1.f); }
    l = gv.z; if ((unsigned)(l - 1) < 16u) { atomicAdd(&ms[base + l], fv.z); atomicAdd(&mc[base + l], 1.f); }
    l = gv.w; if ((unsigned)(l - 1) < 16u) { atomicAdd(&ms[base + l], fv.w); atomicAdd(&mc[base + l], 1.f); }
  }
  __syncthreads();

  float* cp = cnt + s.scale * NSEG;
  for (int i = tid; i < NSEG; i += 256) {
    float sv = s_sum[0][i] + s_sum[1][i] + s_sum[2][i] + s_sum[3][i];
    float cv = s_cnt[0][i] + s_cnt[1][i] + s_cnt[2][i] + s_cnt[3][i];
    if (cv != 0.f) {
      gatomic_add(&tot_sum[i], sv);
      gatomic_add(&cp[i], cv);
    }
  }
}

__global__ __launch_bounds__(256) void mean_kernel(
    const float* __restrict__ tot_sum, const float* __restrict__ cnt,
    float* __restrict__ mean, float* __restrict__ tot_cnt) {
  for (int i = threadIdx.x; i < NSEG; i += 256) {
    float c = cnt[i] + cnt[NSEG + i] + cnt[2 * NSEG + i];
    tot_cnt[i] = c;
    mean[i] = tot_sum[i] / fmaxf(c, 1.f);
  }
}

__global__ __launch_bounds__(256, 4) void pass2_kernel(
    const float4* __restrict__ f0, const int4* __restrict__ g0,
    const float4* __restrict__ f1, const int4* __restrict__ g1,
    const float4* __restrict__ f2, const int4* __restrict__ g2,
    const float* __restrict__ mean,
    float* __restrict__ pull)      // [3][NSEG]
{
  __shared__ float s_val[NW][NSEG];
  __shared__ float s_mean[NSEG];
  const int tid = threadIdx.x;
  const int wave = tid >> 6;
  for (int i = tid; i < NW * NSEG; i += 256) (&s_val[0][0])[i] = 0.f;
  for (int i = tid; i < NSEG; i += 256) s_mean[i] = mean[i];
  __syncthreads();

  ScaleSel s = select_scale(blockIdx.x, f0, g0, f1, g1, f2, g2);
  float* mv = s_val[wave];

  for (int v = s.vstart * 256 + tid; v < s.nvec; v += s.nblocks * 256) {
    float4 fv = s.f[v];
    int4   gv = s.g[v];
    int base = (v >> s.logSv) * 17;
    int l; float d;
    l = gv.x; if ((unsigned)(l - 1) < 16u) { d = fmaxf(fabsf(fv.x - s_mean[base + l]) - M_VAR, 0.f); atomicAdd(&mv[base + l], d * d); }
    l = gv.y; if ((unsigned)(l - 1) < 16u) { d = fmaxf(fabsf(fv.y - s_mean[base + l]) - M_VAR, 0.f); atomicAdd(&mv[base + l], d * d); }
    l = gv.z; if ((unsigned)(l - 1) < 16u) { d = fmaxf(fabsf(fv.z - s_mean[base + l]) - M_VAR, 0.f); atomicAdd(&mv[base + l], d * d); }
    l = gv.w; if ((unsigned)(l - 1) < 16u) { d = fmaxf(fabsf(fv.w - s_mean[base + l]) - M_VAR, 0.f); atomicAdd(&mv[base + l], d * d); }
  }
  __syncthreads();

  float* pp = pull + s.scale * NSEG;
  for (int i = tid; i < NSEG; i += 256) {
    float sv = s_val[0][i] + s_val[1][i] + s_val[2][i] + s_val[3][i];
    if (sv != 0.f) gatomic_add(&pp[i], sv);
  }
}

__global__ __launch_bounds__(256) void finalize_kernel(
    const float* __restrict__ tot_cnt, const float* __restrict__ mean,
    const float* __restrict__ cnt, const float* __restrict__ pull,
    float* __restrict__ out) {
  __shared__ float s_mean[NSEG];
  __shared__ unsigned char s_pres[NSEG];
  const int t = threadIdx.x;
  for (int i = t; i < NSEG; i += 256) {
    s_mean[i] = mean[i];
    s_pres[i] = (tot_cnt[i] > 0.f) ? 1 : 0;
  }
  __syncthreads();

  float pull_v = 0.f, pull_n = 0.f, push_v = 0.f, push_n = 0.f;

  // pull: per present instance, sum over scales of (pull_s / cnt_s) where cnt_s>0
  for (int i = t; i < NSEG; i += 256) {
    int lab = i - (i / 17) * 17;
    if (lab >= 1 && s_pres[i]) {
      float ps = 0.f;
      float c0 = cnt[i];            if (c0 > 0.f) ps += pull[i] / c0;
      float c1 = cnt[NSEG + i];     if (c1 > 0.f) ps += pull[NSEG + i] / c1;
      float c2 = cnt[2 * NSEG + i]; if (c2 > 0.f) ps += pull[2 * NSEG + i] / c2;
      pull_v += ps;
      pull_n += 1.f;
    }
  }

  // push: thread t -> (b = t/16, i = t%16); loop j; ordered pairs i != j
  {
    int b = t >> 4, ii = t & 15;
    int si = b * 17 + ii + 1;
    if (s_pres[si]) {
      float mi = s_mean[si];
      for (int j = 0; j < 16; ++j) {
        if (j == ii) continue;
        int sj = b * 17 + j + 1;
        if (s_pres[sj]) {
          float d = fmaxf(TWO_M_DIST - fabsf(mi - s_mean[sj]), 0.f);
          push_v += d * d;
          push_n += 1.f;
        }
      }
    }
  }

  // reduce 4 values across 256 threads: wave64 shuffle then LDS across 4 waves
  #pragma unroll
  for (int o = 32; o > 0; o >>= 1) {
    pull_v += __shfl_down(pull_v, o);
    pull_n += __shfl_down(pull_n, o);
    push_v += __shfl_down(push_v, o);
    push_n += __shfl_down(push_n, o);
  }
  __shared__ float r[NW][4];
  int wave = t >> 6;
  if ((t & 63) == 0) { r[wave][0] = pull_v; r[wave][1] = pull_n; r[wave][2] = push_v; r[wave][3] = push_n; }
  __syncthreads();
  if (t == 0) {
    float PV = 0, PN = 0, SV = 0, SN = 0;
    for (int w = 0; w < NW; ++w) { PV += r[w][0]; PN += r[w][1]; SV += r[w][2]; SN += r[w][3]; }
    float pull_loss = PV / fmaxf(PN, 1.f);  // VAR_W = 1.0
    float push_loss = SV / fmaxf(SN, 1.f);  // DIST_W = 1.0
    out[0] = pull_loss + push_loss;
  }
}

extern "C" void kernel_launch(void* const* d_in, const int* in_sizes, int n_in,
                              void* d_out, int out_size, void* d_ws, size_t ws_size,
                              hipStream_t stream) {
  // setup_inputs() dict order: featmap0, gt0, featmap1, gt1, featmap2, gt2
  const float4* f0 = (const float4*)d_in[0];
  const int4*   g0 = (const int4*)  d_in[1];
  const float4* f1 = (const float4*)d_in[2];
  const int4*   g1 = (const int4*)  d_in[3];
  const float4* f2 = (const float4*)d_in[4];
  const int4*   g2 = (const int4*)  d_in[5];

  float* ws      = (float*)d_ws;
  float* tot_sum = ws;                // [NSEG]
  float* cnt     = ws + NSEG;         // [3][NSEG]
  float* pull    = ws + 4 * NSEG;     // [3][NSEG]
  float* mean    = ws + 7 * NSEG;     // [NSEG]
  float* tot_cnt = ws + 8 * NSEG;     // [NSEG]

  hipMemsetAsync(d_ws, 0, 7 * NSEG * sizeof(float), stream);  // zero accumulators
  pass1_kernel<<<GRID_BLOCKS, 256, 0, stream>>>(f0, g0, f1, g1, f2, g2, tot_sum, cnt);
  mean_kernel<<<1, 256, 0, stream>>>(tot_sum, cnt, mean, tot_cnt);
  pass2_kernel<<<GRID_BLOCKS, 256, 0, stream>>>(f0, g0, f1, g1, f2, g2, mean, pull);
  finalize_kernel<<<1, 256, 0, stream>>>(tot_cnt, mean, cnt, pull, (float*)d_out);
}

// Round 2
// 213.939 us; speedup vs baseline: 2.3483x; 2.3483x over previous
//
#include <hip/hip_runtime.h>

// MSPushPullLoss: B=16, C=16, labels 0..16, seg = b*17+lab, NSEG=272.
// Scales: (16,1024,1024) (16,512,512) (16,256,256) -> float4 vec counts 2^20*4,... per batch 2^18/2^16/2^14.
// R2: per-thread private LDS bins (no atomics). Each block owns one batch.
// bins laid out [label][256] -> bank = t%32 always (2-way aliasing, free).

#define NSEG 272
#define M_VAR 0.1f
#define TWO_M_DIST 3.0f

__device__ __forceinline__ void gatomic_add(float* p, float v) {
  __hip_atomic_fetch_add(p, v, __ATOMIC_RELAXED, __HIP_MEMORY_SCOPE_AGENT);
}

// Grid: scale0 = 16 batches x 48 sub-blocks = 768 blocks
//       scale1 = 16 x 12 = 192   (blocks 768..959)
//       scale2 = 16 x 3  = 48    (blocks 960..1007)
// 1008 blocks, all co-resident at 4 blocks/CU.
#define GRID_BLOCKS 1008

struct Sel {
  const float4* f; const int4* g;
  int vbase, vend, stride, scale, batch;
};

__device__ __forceinline__ Sel pick(
    int b, int t,
    const float4* f0, const int4* g0,
    const float4* f1, const int4* g1,
    const float4* f2, const int4* g2) {
  Sel s;
  if (b < 768) {
    int batch = b / 48, sub = b - batch * 48;
    s.f = f0; s.g = g0; s.scale = 0; s.batch = batch;
    s.vbase = batch * 262144 + sub * 256 + t;
    s.vend  = (batch + 1) * 262144;
    s.stride = 48 * 256;
  } else if (b < 960) {
    int lb = b - 768; int batch = lb / 12, sub = lb - batch * 12;
    s.f = f1; s.g = g1; s.scale = 1; s.batch = batch;
    s.vbase = batch * 65536 + sub * 256 + t;
    s.vend  = (batch + 1) * 65536;
    s.stride = 12 * 256;
  } else {
    int lb = b - 960; int batch = lb / 3, sub = lb - batch * 3;
    s.f = f2; s.g = g2; s.scale = 2; s.batch = batch;
    s.vbase = batch * 16384 + sub * 256 + t;
    s.vend  = (batch + 1) * 16384;
    s.stride = 3 * 256;
  }
  return s;
}

// ---------------- pass 1: per-(batch,label) sum + per-scale count ----------------
__global__ __launch_bounds__(256, 4) void pass1_kernel(
    const float4* __restrict__ f0, const int4* __restrict__ g0,
    const float4* __restrict__ f1, const int4* __restrict__ g1,
    const float4* __restrict__ f2, const int4* __restrict__ g2,
    float* __restrict__ tot_sum,   // [NSEG]
    float* __restrict__ cnt)       // [3][NSEG]
{
  __shared__ float2 bins[17 * 256];   // [label][thread] {sum, count} -- 34816 B
  const int t = threadIdx.x;
  for (int i = t; i < 17 * 256; i += 256) bins[i] = make_float2(0.f, 0.f);
  __syncthreads();

  Sel s = pick(blockIdx.x, t, f0, g0, f1, g1, f2, g2);

  for (int v = s.vbase; v < s.vend; v += s.stride) {
    float4 fv = s.f[v];
    int4   gv = s.g[v];
    // label 0 = background -> bin 0 (never read); labels are 0..16 by construction.
    {
      int idx = (int)min((unsigned)gv.x, 16u) * 256 + t;
      float2 r = bins[idx]; bins[idx] = make_float2(r.x + fv.x, r.y + 1.f);
    }
    {
      int idx = (int)min((unsigned)gv.y, 16u) * 256 + t;
      float2 r = bins[idx]; bins[idx] = make_float2(r.x + fv.y, r.y + 1.f);
    }
    {
      int idx = (int)min((unsigned)gv.z, 16u) * 256 + t;
      float2 r = bins[idx]; bins[idx] = make_float2(r.x + fv.z, r.y + 1.f);
    }
    {
      int idx = (int)min((unsigned)gv.w, 16u) * 256 + t;
      float2 r = bins[idx]; bins[idx] = make_float2(r.x + fv.w, r.y + 1.f);
    }
  }

  // tree-reduce over the thread dimension: [17][256] -> [17][1]
  for (int sh = 7; sh >= 0; --sh) {
    __syncthreads();
    int off = 1 << sh;
    for (int i = t; i < 17 * off; i += 256) {
      int l = i >> sh, tt = i & (off - 1);
      int a = l * 256 + tt;
      float2 x = bins[a], y = bins[a + off];
      bins[a] = make_float2(x.x + y.x, x.y + y.y);
    }
  }
  __syncthreads();

  if (t >= 1 && t < 17) {
    float2 r = bins[t * 256];
    if (r.y != 0.f) {
      gatomic_add(&tot_sum[s.batch * 17 + t], r.x);
      gatomic_add(&cnt[s.scale * NSEG + s.batch * 17 + t], r.y);
    }
  }
}

// ---------------- mean ----------------
__global__ __launch_bounds__(256) void mean_kernel(
    const float* __restrict__ tot_sum, const float* __restrict__ cnt,
    float* __restrict__ mean, float* __restrict__ tot_cnt) {
  for (int i = threadIdx.x; i < NSEG; i += 256) {
    float c = cnt[i] + cnt[NSEG + i] + cnt[2 * NSEG + i];
    tot_cnt[i] = c;
    mean[i] = tot_sum[i] / fmaxf(c, 1.f);
  }
}

// ---------------- pass 2: per-(scale,batch,label) pull sums ----------------
__global__ __launch_bounds__(256, 8) void pass2_kernel(
    const float4* __restrict__ f0, const int4* __restrict__ g0,
    const float4* __restrict__ f1, const int4* __restrict__ g1,
    const float4* __restrict__ f2, const int4* __restrict__ g2,
    const float* __restrict__ mean,
    float* __restrict__ pull)      // [3][NSEG]
{
  __shared__ float bins[17 * 256];  // 17408 B
  __shared__ float s_mean[17];
  const int t = threadIdx.x;

  Sel s = pick(blockIdx.x, t, f0, g0, f1, g1, f2, g2);

  for (int i = t; i < 17 * 256; i += 256) bins[i] = 0.f;
  if (t < 17) s_mean[t] = mean[s.batch * 17 + t];
  __syncthreads();

  for (int v = s.vbase; v < s.vend; v += s.stride) {
    float4 fv = s.f[v];
    int4   gv = s.g[v];
    // invalid (label 0) falls into bin 0 with garbage mean(=0) -- bin 0 never read.
    {
      int l = (int)min((unsigned)gv.x, 16u);
      float d = fmaxf(fabsf(fv.x - s_mean[l]) - M_VAR, 0.f);
      bins[l * 256 + t] += d * d;
    }
    {
      int l = (int)min((unsigned)gv.y, 16u);
      float d = fmaxf(fabsf(fv.y - s_mean[l]) - M_VAR, 0.f);
      bins[l * 256 + t] += d * d;
    }
    {
      int l = (int)min((unsigned)gv.z, 16u);
      float d = fmaxf(fabsf(fv.z - s_mean[l]) - M_VAR, 0.f);
      bins[l * 256 + t] += d * d;
    }
    {
      int l = (int)min((unsigned)gv.w, 16u);
      float d = fmaxf(fabsf(fv.w - s_mean[l]) - M_VAR, 0.f);
      bins[l * 256 + t] += d * d;
    }
  }

  for (int sh = 7; sh >= 0; --sh) {
    __syncthreads();
    int off = 1 << sh;
    for (int i = t; i < 17 * off; i += 256) {
      int l = i >> sh, tt = i & (off - 1);
      bins[l * 256 + tt] += bins[l * 256 + tt + off];
    }
  }
  __syncthreads();

  if (t >= 1 && t < 17) {
    float r = bins[t * 256];
    if (r != 0.f) gatomic_add(&pull[s.scale * NSEG + s.batch * 17 + t], r);
  }
}

// ---------------- finalize ----------------
__global__ __launch_bounds__(256) void finalize_kernel(
    const float* __restrict__ tot_cnt, const float* __restrict__ mean,
    const float* __restrict__ cnt, const float* __restrict__ pull,
    float* __restrict__ out) {
  __shared__ float s_mean[NSEG];
  __shared__ unsigned char s_pres[NSEG];
  const int t = threadIdx.x;
  for (int i = t; i < NSEG; i += 256) {
    s_mean[i] = mean[i];
    s_pres[i] = (tot_cnt[i] > 0.f) ? 1 : 0;
  }
  __syncthreads();

  float pull_v = 0.f, pull_n = 0.f, push_v = 0.f, push_n = 0.f;

  for (int i = t; i < NSEG; i += 256) {
    int lab = i - (i / 17) * 17;
    if (lab >= 1 && s_pres[i]) {
      float ps = 0.f;
      float c0 = cnt[i];            if (c0 > 0.f) ps += pull[i] / c0;
      float c1 = cnt[NSEG + i];     if (c1 > 0.f) ps += pull[NSEG + i] / c1;
      float c2 = cnt[2 * NSEG + i]; if (c2 > 0.f) ps += pull[2 * NSEG + i] / c2;
      pull_v += ps;
      pull_n += 1.f;
    }
  }

  {
    int b = t >> 4, ii = t & 15;
    int si = b * 17 + ii + 1;
    if (s_pres[si]) {
      float mi = s_mean[si];
      for (int j = 0; j < 16; ++j) {
        if (j == ii) continue;
        int sj = b * 17 + j + 1;
        if (s_pres[sj]) {
          float d = fmaxf(TWO_M_DIST - fabsf(mi - s_mean[sj]), 0.f);
          push_v += d * d;
          push_n += 1.f;
        }
      }
    }
  }

  #pragma unroll
  for (int o = 32; o > 0; o >>= 1) {
    pull_v += __shfl_down(pull_v, o);
    pull_n += __shfl_down(pull_n, o);
    push_v += __shfl_down(push_v, o);
    push_n += __shfl_down(push_n, o);
  }
  __shared__ float r[4][4];
  int wave = t >> 6;
  if ((t & 63) == 0) { r[wave][0] = pull_v; r[wave][1] = pull_n; r[wave][2] = push_v; r[wave][3] = push_n; }
  __syncthreads();
  if (t == 0) {
    float PV = 0, PN = 0, SV = 0, SN = 0;
    for (int w = 0; w < 4; ++w) { PV += r[w][0]; PN += r[w][1]; SV += r[w][2]; SN += r[w][3]; }
    out[0] = PV / fmaxf(PN, 1.f) + SV / fmaxf(SN, 1.f);
  }
}

extern "C" void kernel_launch(void* const* d_in, const int* in_sizes, int n_in,
                              void* d_out, int out_size, void* d_ws, size_t ws_size,
                              hipStream_t stream) {
  // setup_inputs() dict order: featmap0, gt0, featmap1, gt1, featmap2, gt2
  const float4* f0 = (const float4*)d_in[0];
  const int4*   g0 = (const int4*)  d_in[1];
  const float4* f1 = (const float4*)d_in[2];
  const int4*   g1 = (const int4*)  d_in[3];
  const float4* f2 = (const float4*)d_in[4];
  const int4*   g2 = (const int4*)  d_in[5];

  float* ws      = (float*)d_ws;
  float* tot_sum = ws;                // [NSEG]
  float* cnt     = ws + NSEG;         // [3][NSEG]
  float* pull    = ws + 4 * NSEG;     // [3][NSEG]
  float* mean    = ws + 7 * NSEG;     // [NSEG]
  float* tot_cnt = ws + 8 * NSEG;     // [NSEG]

  hipMemsetAsync(d_ws, 0, 7 * NSEG * sizeof(float), stream);
  pass1_kernel<<<GRID_BLOCKS, 256, 0, stream>>>(f0, g0, f1, g1, f2, g2, tot_sum, cnt);
  mean_kernel<<<1, 256, 0, stream>>>(tot_sum, cnt, mean, tot_cnt);
  pass2_kernel<<<GRID_BLOCKS, 256, 0, stream>>>(f0, g0, f1, g1, f2, g2, mean, pull);
  finalize_kernel<<<1, 256, 0, stream>>>(tot_cnt, mean, cnt, pull, (float*)d_out);
}